// Round 6
// baseline (33.274 us; speedup 1.0000x reference)
//
#include <hip/hip_runtime.h>

constexpr int KSZ     = 16;
constexpr int STRIDE  = 4;
constexpr int NROWS   = 4096;
constexpr int LCOLS   = 8192;
constexpr int OUT_LEN = (LCOLS - KSZ) / STRIDE + 1;  // 2045
constexpr int BLOCK   = 512;
constexpr int NF4     = LCOLS / 4;                   // 2048 float4 per row

// Involution XOR swizzle on float4 index (low 3 bits ^= f(high bits)).
// Read side (q = 4*lane + j): uniform bank-group spread, conflict-free.
// Involution => same function maps global->LDS slot and LDS slot->global.
__device__ __forceinline__ int swz(int q) {
    return q ^ (((q >> 3) ^ (q >> 6)) & 7);
}

__global__ __launch_bounds__(BLOCK) void or_conv_kernel(
    const float* __restrict__ x, const float* __restrict__ w,
    float* __restrict__ out)
{
    __shared__ float4 smem[NF4];   // 32 KB: one full input row

    const int t = threadIdx.x;
    const int n = blockIdx.x;
    const int wv = t >> 6;         // wave 0..7
    const int l  = t & 63;         // lane

    // Pre-scale weights by log2(e): exp(rho) = exp2(rho*log2e);
    // sum(rho*e) = ln2 * sum(tt*e).
    float wr2[KSZ];
#pragma unroll
    for (int k = 0; k < KSZ; ++k) wr2[k] = w[k] * 1.44269504089f;

    // Stage row -> LDS via global_load_lds width=16 (no VGPR round-trip).
    // Rule #21 pattern: LINEAR LDS dest (wave-uniform base + lane*16),
    // PRE-SWIZZLED global source (lane l fetches swz(64c+l); swz permutes
    // only within 8-float4 groups -> wave still covers one contiguous 1KB
    // span, coalescing intact), and swz() on the read side. swz is an
    // involution so source-perm == read-perm.
    const float4* rowp4 = reinterpret_cast<const float4*>(x + (size_t)n * LCOLS);
#pragma unroll
    for (int j = 0; j < 4; ++j) {
        const int c  = 4 * wv + j;              // chunk of 64 float4s
        const int gq = swz(64 * c + l);         // pre-swizzled global index
        __builtin_amdgcn_global_load_lds(
            reinterpret_cast<const uint32_t*>(rowp4 + gq),
            reinterpret_cast<uint32_t*>(&smem[64 * c]),
            16, 0, 0);
    }
    __syncthreads();   // drains vmcnt + barrier

    // Thread t computes 4 consecutive outputs 4t..4t+3: windows span float4
    // positions 4t..4t+6 -> 7 ds_read_b128 per 4 outputs.
    float4 f[7];
#pragma unroll
    for (int j = 0; j < 7; ++j) {
        const int q = min(4 * t + j, NF4 - 1);  // clamp tail (thread 511)
        f[j] = smem[swz(q)];
    }
    const float* win = reinterpret_cast<const float*>(f);  // 28 floats

    float res[4];
#pragma unroll
    for (int i = 0; i < 4; ++i) {
        float se = 0.f, sr = 0.f;
#pragma unroll
        for (int k = 0; k < KSZ; ++k) {
            const float tt = win[STRIDE * i + k] * wr2[k];  // rho*log2e
            const float e  = __builtin_amdgcn_exp2f(tt);
            se += e;
            sr  = fmaf(tt, e, sr);
        }
        res[i] = sr * 0.69314718056f * __builtin_amdgcn_rcpf(se);
    }

    // 4 consecutive dword stores, NORMAL cached (L2 merges lane-scatter;
    // round-2 lesson: nontemporal scatter = 3.8x HBM write RMW).
    float* op = out + (size_t)n * OUT_LEN + 4 * t;
#pragma unroll
    for (int i = 0; i < 4; ++i) {
        if (4 * t + i < OUT_LEN) op[i] = res[i];
    }
}

extern "C" void kernel_launch(void* const* d_in, const int* in_sizes, int n_in,
                              void* d_out, int out_size, void* d_ws, size_t ws_size,
                              hipStream_t stream)
{
    const float* x = (const float*)d_in[0];
    const float* w = (const float*)d_in[1];
    float* out     = (float*)d_out;

    or_conv_kernel<<<dim3(NROWS), dim3(BLOCK), 0, stream>>>(x, w, out);
}

// Round 7
// 30.163 us; speedup vs baseline: 1.1031x; 1.1031x over previous
//
#include <hip/hip_runtime.h>

typedef __attribute__((ext_vector_type(2))) float f2;

constexpr int KSZ     = 16;
constexpr int STRIDE  = 4;
constexpr int NROWS   = 4096;
constexpr int LCOLS   = 8192;
constexpr int OUT_LEN = (LCOLS - KSZ) / STRIDE + 1;  // 2045
constexpr int BLOCK   = 512;
constexpr int NF4     = LCOLS / 4;                   // 2048 float4 per row

// Involution XOR swizzle on float4 index (r5-proven: conflict-free on both
// the consecutive-write and 4t-strided-read patterns).
__device__ __forceinline__ int swz(int q) {
    return q ^ (((q >> 3) ^ (q >> 6)) & 7);
}

__global__ __launch_bounds__(BLOCK) void or_conv_kernel(
    const float* __restrict__ x, const float* __restrict__ w,
    float* __restrict__ out)
{
    __shared__ float4 smem[NF4];   // 32 KB: one full input row

    const int t = threadIdx.x;
    const int n = blockIdx.x;

    // Weight pairs pre-scaled by log2(e): exp(rho)=exp2(rho*log2e);
    // Σ rho·e = ln2 · Σ tt·e.
    f2 w2[KSZ / 2];
#pragma unroll
    for (int k = 0; k < KSZ / 2; ++k) {
        w2[k].x = w[2 * k]     * 1.44269504089f;
        w2[k].y = w[2 * k + 1] * 1.44269504089f;
    }

    // Stage row -> LDS (r5 path: plain ds_write; r6 showed global_load_lds
    // is a regression here). 4 lane-contiguous float4 loads, 1x L1 traffic.
    const float4* rowp4 = reinterpret_cast<const float4*>(x + (size_t)n * LCOLS);
#pragma unroll
    for (int j = 0; j < 4; ++j) {
        const int pos = t + BLOCK * j;          // covers 0..2047 exactly
        smem[swz(pos)] = rowp4[pos];
    }
    __syncthreads();

    // Thread t: 4 consecutive outputs 4t..4t+3, windows span float4
    // positions 4t..4t+6 -> 7 ds_read_b128.
    float4 f[7];
#pragma unroll
    for (int j = 0; j < 7; ++j) {
        const int q = min(4 * t + j, NF4 - 1);  // clamp tail (thread 511)
        f[j] = smem[swz(q)];
    }
    const float* win = reinterpret_cast<const float*>(f);  // 28 floats

    // Packed-f32 math: window pairs are 8B-aligned (start 4i even), so the
    // mul/add/fma stream maps to v_pk_{mul,add,fma}_f32 (VOP3P) - half the
    // VALU instructions. exp2 stays scalar (no packed trans pipe).
    float res[4];
#pragma unroll
    for (int i = 0; i < 4; ++i) {
        f2 se2 = {0.f, 0.f}, sr2 = {0.f, 0.f};
#pragma unroll
        for (int kk = 0; kk < KSZ / 2; ++kk) {
            const f2 v  = *reinterpret_cast<const f2*>(win + STRIDE * i + 2 * kk);
            const f2 tt = v * w2[kk];                       // v_pk_mul_f32
            f2 e;
            e.x = __builtin_amdgcn_exp2f(tt.x);
            e.y = __builtin_amdgcn_exp2f(tt.y);
            se2 += e;                                        // v_pk_add_f32
            sr2 += tt * e;                                   // v_pk_fma_f32
        }
        const float se = se2.x + se2.y;
        const float sr = sr2.x + sr2.y;
        res[i] = sr * 0.69314718056f * __builtin_amdgcn_rcpf(se);
    }

    // 4 consecutive dword stores, NORMAL cached (round-2 lesson:
    // nontemporal lane-scatter = partial-line RMW).
    float* op = out + (size_t)n * OUT_LEN + 4 * t;
#pragma unroll
    for (int i = 0; i < 4; ++i) {
        if (4 * t + i < OUT_LEN) op[i] = res[i];
    }
}

extern "C" void kernel_launch(void* const* d_in, const int* in_sizes, int n_in,
                              void* d_out, int out_size, void* d_ws, size_t ws_size,
                              hipStream_t stream)
{
    const float* x = (const float*)d_in[0];
    const float* w = (const float*)d_in[1];
    float* out     = (float*)d_out;

    or_conv_kernel<<<dim3(NROWS), dim3(BLOCK), 0, stream>>>(x, w, out);
}